// Round 2
// baseline (804.887 us; speedup 1.0000x reference)
//
#include <hip/hip_runtime.h>

// LSTM autoencoder, fully fused. B=8192, T=30, F=16, H1=64, H2=32.
// Phase A: L1(64) + L2(32) stepwise -> latent. Phase B: L3(32) + L4(64) + out proj.
// One block per CU (grid=256), 512 threads, batch tile BT=32.
// Weights in LDS, transposed + gate-interleaved: wT[k][j][gate] (float4 per (k,j)).
// Activations in LDS transposed with +1-row pad: aT[row][b], row stride 33.

#define TT 30
#define FF 16

constexpr int NT = 512;   // threads per block
constexpr int BT = 32;    // batch elements per block

__device__ __forceinline__ float sigf(float v) { return 1.f / (1.f + __expf(-v)); }
__device__ __forceinline__ float tanhf_(float v) { return 2.f / (1.f + __expf(-2.f * v)) - 1.f; }

__global__ __launch_bounds__(NT, 2) void lstm_ae_kernel(
    const float* __restrict__ x,
    const float* __restrict__ Wih1, const float* __restrict__ Whh1, const float* __restrict__ b1,
    const float* __restrict__ Wih2, const float* __restrict__ Whh2, const float* __restrict__ b2,
    const float* __restrict__ Wih3, const float* __restrict__ Whh3, const float* __restrict__ b3,
    const float* __restrict__ Wih4, const float* __restrict__ Whh4, const float* __restrict__ b4,
    const float* __restrict__ Wout, const float* __restrict__ bout,
    float* __restrict__ out)
{
  // LDS carve: weights 33792 f (132KB), biases 448 f, activations 128x33 f (16.5KB), y 32x17 f
  __shared__ __align__(16) float wS[33792];
  __shared__ __align__(16) float bS[448];
  __shared__ __align__(16) float aT[128 * 33];
  __shared__ __align__(16) float yS[32 * 17];

  const int t  = threadIdx.x;
  const int bl = t & 15;     // batch sub-lane: handles bl and bl+16
  const int g  = t >> 4;     // unit group 0..31
  const int bBase = blockIdx.x * BT;

  // ================= Phase A staging =================
  // W1s: wS[(k*64 + j)*4 + q] = row (q*64+j) of [Wih1 | Whh1], k in [0,80)
  for (int i = t; i < 20480; i += NT) {
    int q = i & 3, j = (i >> 2) & 63, k = i >> 8;
    int u = q * 64 + j;
    wS[i] = (k < 16) ? Wih1[u * 16 + k] : Whh1[u * 64 + (k - 16)];
  }
  // W2s: wS[20480 + (k*32 + j)*4 + q], k in [0,96)
  for (int i = t; i < 12288; i += NT) {
    int q = i & 3, j = (i >> 2) & 31, k = i >> 7;
    int u = q * 32 + j;
    wS[20480 + i] = (k < 64) ? Wih2[u * 64 + k] : Whh2[u * 32 + (k - 64)];
  }
  if (t < 256) bS[(t & 63) * 4 + (t >> 6)] = b1[t];
  else if (t < 384) { int u = t - 256; bS[256 + (u & 31) * 4 + (u >> 5)] = b2[u]; }
  // zero h1 (rows 16..79) and h2 (rows 80..111)
  for (int i = t; i < 96 * 33; i += NT) aT[16 * 33 + i] = 0.f;
  // stage x(t=0) into rows 0..15 (coalesced read, pad-33 avoids LDS write conflicts)
  {
    int b = t >> 4, f = t & 15;
    aT[f * 33 + b] = x[(size_t)(bBase + b) * (TT * FF) + f];
  }
  __syncthreads();

  float c1[2][2] = {{0.f, 0.f}, {0.f, 0.f}};
  float c2[2]    = {0.f, 0.f};

  // ================= Phase A: encoder =================
  for (int st = 0; st < TT; ++st) {
    // ---- z1: units j=2g,2g+1, gates q0..3, batches bl,bl+16 ----
    float z1[2][4][2];
    {
      const float4 bv0 = *(const float4*)&bS[(2 * g) * 4];
      const float4 bv1 = *(const float4*)&bS[(2 * g + 1) * 4];
      z1[0][0][0] = z1[0][0][1] = bv0.x; z1[0][1][0] = z1[0][1][1] = bv0.y;
      z1[0][2][0] = z1[0][2][1] = bv0.z; z1[0][3][0] = z1[0][3][1] = bv0.w;
      z1[1][0][0] = z1[1][0][1] = bv1.x; z1[1][1][0] = z1[1][1][1] = bv1.y;
      z1[1][2][0] = z1[1][2][1] = bv1.z; z1[1][3][0] = z1[1][3][1] = bv1.w;
    }
    for (int k = 0; k < 80; ++k) {
      float a0 = aT[k * 33 + bl];
      float a1 = aT[k * 33 + bl + 16];
      const float4 w0 = *(const float4*)&wS[(k * 64 + 2 * g) * 4];
      const float4 w1 = *(const float4*)&wS[(k * 64 + 2 * g + 1) * 4];
      z1[0][0][0] += w0.x * a0; z1[0][0][1] += w0.x * a1;
      z1[0][1][0] += w0.y * a0; z1[0][1][1] += w0.y * a1;
      z1[0][2][0] += w0.z * a0; z1[0][2][1] += w0.z * a1;
      z1[0][3][0] += w0.w * a0; z1[0][3][1] += w0.w * a1;
      z1[1][0][0] += w1.x * a0; z1[1][0][1] += w1.x * a1;
      z1[1][1][0] += w1.y * a0; z1[1][1][1] += w1.y * a1;
      z1[1][2][0] += w1.z * a0; z1[1][2][1] += w1.z * a1;
      z1[1][3][0] += w1.w * a0; z1[1][3][1] += w1.w * a1;
    }
    __syncthreads();  // all reads of old h1 done
    // ---- h1/c1 update (c in registers, h -> rows 16..79) ----
#pragma unroll
    for (int jj = 0; jj < 2; ++jj)
#pragma unroll
      for (int bb = 0; bb < 2; ++bb) {
        float iv = sigf(z1[jj][0][bb]);
        float fv = sigf(z1[jj][1][bb]);
        float gv = tanhf_(z1[jj][2][bb]);
        float ov = sigf(z1[jj][3][bb]);
        float c  = fv * c1[jj][bb] + iv * gv;
        c1[jj][bb] = c;
        aT[(16 + 2 * g + jj) * 33 + bl + 16 * bb] = ov * tanhf_(c);
      }
    __syncthreads();  // h1 ready
    // ---- stage x(st+1) (rows 0..15, not read by z2) ----
    if (st + 1 < TT) {
      int b = t >> 4, f = t & 15;
      aT[f * 33 + b] = x[(size_t)(bBase + b) * (TT * FF) + (st + 1) * FF + f];
    }
    // ---- z2: unit j=g, input rows 16..111 (h1 new | h2 old) ----
    float z2[4][2];
    {
      const float4 bv = *(const float4*)&bS[256 + g * 4];
      z2[0][0] = z2[0][1] = bv.x; z2[1][0] = z2[1][1] = bv.y;
      z2[2][0] = z2[2][1] = bv.z; z2[3][0] = z2[3][1] = bv.w;
    }
    for (int k = 0; k < 96; ++k) {
      float a0 = aT[(16 + k) * 33 + bl];
      float a1 = aT[(16 + k) * 33 + bl + 16];
      const float4 w = *(const float4*)&wS[20480 + (k * 32 + g) * 4];
      z2[0][0] += w.x * a0; z2[0][1] += w.x * a1;
      z2[1][0] += w.y * a0; z2[1][1] += w.y * a1;
      z2[2][0] += w.z * a0; z2[2][1] += w.z * a1;
      z2[3][0] += w.w * a0; z2[3][1] += w.w * a1;
    }
    __syncthreads();  // all reads of old h2 done
#pragma unroll
    for (int bb = 0; bb < 2; ++bb) {
      float iv = sigf(z2[0][bb]);
      float fv = sigf(z2[1][bb]);
      float gv = tanhf_(z2[2][bb]);
      float ov = sigf(z2[3][bb]);
      float c  = fv * c2[bb] + iv * gv;
      c2[bb] = c;
      aT[(80 + g) * 33 + bl + 16 * bb] = ov * tanhf_(c);
    }
    __syncthreads();  // h2 ready (next step / latent)
  }

  // ================= Transition: latent = final h2 -> rows 96..127 =================
  float l0, l1;
  {
    int v1 = t + 512;
    l0 = aT[(80 + (t  >> 5)) * 33 + (t  & 31)];
    l1 = aT[(80 + (v1 >> 5)) * 33 + (v1 & 31)];
  }
  __syncthreads();
  {
    int v1 = t + 512;
    aT[(96 + (t  >> 5)) * 33 + (t  & 31)] = l0;
    aT[(96 + (v1 >> 5)) * 33 + (v1 & 31)] = l1;
  }
  // zero h3 (rows 0..31) and h4 (rows 32..95)
  for (int i = t; i < 96 * 33; i += NT) aT[i] = 0.f;
  // ---- Phase B weights ----
  for (int i = t; i < 8192; i += NT) {       // W3s: k in [0,64): [Wih3 | Whh3]
    int q = i & 3, j = (i >> 2) & 31, k = i >> 7;
    int u = q * 32 + j;
    wS[i] = (k < 32) ? Wih3[u * 32 + k] : Whh3[u * 32 + (k - 32)];
  }
  for (int i = t; i < 24576; i += NT) {      // W4s: k in [0,96): [Wih4 | Whh4]
    int q = i & 3, j = (i >> 2) & 63, k = i >> 8;
    int u = q * 64 + j;
    wS[8192 + i] = (k < 32) ? Wih4[u * 32 + k] : Whh4[u * 64 + (k - 32)];
  }
  for (int i = t; i < 1024; i += NT) {       // Wout^T: wS[32768 + k*16 + o]
    int o = i & 15, k = i >> 4;
    wS[32768 + k * 16 + o] = Wout[o * 64 + k];
  }
  if (t < 128) bS[(t & 31) * 4 + (t >> 5)] = b3[t];
  else if (t < 384) { int u = t - 128; bS[128 + (u & 63) * 4 + (u >> 6)] = b4[u]; }
  else if (t < 400) bS[384 + (t - 384)] = bout[t - 384];
  __syncthreads();

  float c3[2]    = {0.f, 0.f};
  float c4[2][2] = {{0.f, 0.f}, {0.f, 0.f}};

  // ================= Phase B: decoder =================
  for (int st = 0; st < TT; ++st) {
    // ---- z3: unit j=g; k<32: latent rows 96..127; k>=32: h3 rows 0..31 ----
    float z3[4][2];
    {
      const float4 bv = *(const float4*)&bS[g * 4];
      z3[0][0] = z3[0][1] = bv.x; z3[1][0] = z3[1][1] = bv.y;
      z3[2][0] = z3[2][1] = bv.z; z3[3][0] = z3[3][1] = bv.w;
    }
    for (int k = 0; k < 32; ++k) {
      float a0 = aT[(96 + k) * 33 + bl];
      float a1 = aT[(96 + k) * 33 + bl + 16];
      const float4 w = *(const float4*)&wS[(k * 32 + g) * 4];
      z3[0][0] += w.x * a0; z3[0][1] += w.x * a1;
      z3[1][0] += w.y * a0; z3[1][1] += w.y * a1;
      z3[2][0] += w.z * a0; z3[2][1] += w.z * a1;
      z3[3][0] += w.w * a0; z3[3][1] += w.w * a1;
    }
    for (int k = 32; k < 64; ++k) {
      float a0 = aT[(k - 32) * 33 + bl];
      float a1 = aT[(k - 32) * 33 + bl + 16];
      const float4 w = *(const float4*)&wS[(k * 32 + g) * 4];
      z3[0][0] += w.x * a0; z3[0][1] += w.x * a1;
      z3[1][0] += w.y * a0; z3[1][1] += w.y * a1;
      z3[2][0] += w.z * a0; z3[2][1] += w.z * a1;
      z3[3][0] += w.w * a0; z3[3][1] += w.w * a1;
    }
    __syncthreads();
#pragma unroll
    for (int bb = 0; bb < 2; ++bb) {
      float iv = sigf(z3[0][bb]);
      float fv = sigf(z3[1][bb]);
      float gv = tanhf_(z3[2][bb]);
      float ov = sigf(z3[3][bb]);
      float c  = fv * c3[bb] + iv * gv;
      c3[bb] = c;
      aT[g * 33 + bl + 16 * bb] = ov * tanhf_(c);
    }
    __syncthreads();  // h3 ready
    // ---- z4: units j=2g,2g+1; k<32: h3 rows 0..31; k>=32: h4 rows 32..95 ----
    float z4[2][4][2];
    {
      const float4 bv0 = *(const float4*)&bS[128 + (2 * g) * 4];
      const float4 bv1 = *(const float4*)&bS[128 + (2 * g + 1) * 4];
      z4[0][0][0] = z4[0][0][1] = bv0.x; z4[0][1][0] = z4[0][1][1] = bv0.y;
      z4[0][2][0] = z4[0][2][1] = bv0.z; z4[0][3][0] = z4[0][3][1] = bv0.w;
      z4[1][0][0] = z4[1][0][1] = bv1.x; z4[1][1][0] = z4[1][1][1] = bv1.y;
      z4[1][2][0] = z4[1][2][1] = bv1.z; z4[1][3][0] = z4[1][3][1] = bv1.w;
    }
    for (int k = 0; k < 96; ++k) {
      float a0 = aT[k * 33 + bl];
      float a1 = aT[k * 33 + bl + 16];
      const float4 w0 = *(const float4*)&wS[8192 + (k * 64 + 2 * g) * 4];
      const float4 w1 = *(const float4*)&wS[8192 + (k * 64 + 2 * g + 1) * 4];
      z4[0][0][0] += w0.x * a0; z4[0][0][1] += w0.x * a1;
      z4[0][1][0] += w0.y * a0; z4[0][1][1] += w0.y * a1;
      z4[0][2][0] += w0.z * a0; z4[0][2][1] += w0.z * a1;
      z4[0][3][0] += w0.w * a0; z4[0][3][1] += w0.w * a1;
      z4[1][0][0] += w1.x * a0; z4[1][0][1] += w1.x * a1;
      z4[1][1][0] += w1.y * a0; z4[1][1][1] += w1.y * a1;
      z4[1][2][0] += w1.z * a0; z4[1][2][1] += w1.z * a1;
      z4[1][3][0] += w1.w * a0; z4[1][3][1] += w1.w * a1;
    }
    __syncthreads();
#pragma unroll
    for (int jj = 0; jj < 2; ++jj)
#pragma unroll
      for (int bb = 0; bb < 2; ++bb) {
        float iv = sigf(z4[jj][0][bb]);
        float fv = sigf(z4[jj][1][bb]);
        float gv = tanhf_(z4[jj][2][bb]);
        float ov = sigf(z4[jj][3][bb]);
        float c  = fv * c4[jj][bb] + iv * gv;
        c4[jj][bb] = c;
        aT[(32 + 2 * g + jj) * 33 + bl + 16 * bb] = ov * tanhf_(c);
      }
    __syncthreads();  // h4 ready
    // ---- output projection: thread -> (o = t>>5, b = t&31) ----
    {
      int o = t >> 5, b = t & 31;
      float acc = bS[384 + o];
      for (int k = 0; k < 64; ++k)
        acc += aT[(32 + k) * 33 + b] * wS[32768 + k * 16 + o];
      yS[b * 17 + o] = acc;
    }
    __syncthreads();
    // ---- coalesced flush: thread -> (b = t>>4, o = t&15) ----
    {
      int b = t >> 4, o = t & 15;
      out[(size_t)(bBase + b) * (TT * FF) + st * FF + o] = yS[b * 17 + o];
    }
    // no barrier needed: yS next written only after 4 barriers in next iteration
  }
}

extern "C" void kernel_launch(void* const* d_in, const int* in_sizes, int n_in,
                              void* d_out, int out_size, void* d_ws, size_t ws_size,
                              hipStream_t stream) {
  const float* x    = (const float*)d_in[0];
  const float* Wih1 = (const float*)d_in[1];
  const float* Whh1 = (const float*)d_in[2];
  const float* b1   = (const float*)d_in[3];
  const float* Wih2 = (const float*)d_in[4];
  const float* Whh2 = (const float*)d_in[5];
  const float* b2   = (const float*)d_in[6];
  const float* Wih3 = (const float*)d_in[7];
  const float* Whh3 = (const float*)d_in[8];
  const float* b3   = (const float*)d_in[9];
  const float* Wih4 = (const float*)d_in[10];
  const float* Whh4 = (const float*)d_in[11];
  const float* b4   = (const float*)d_in[12];
  const float* Wout = (const float*)d_in[13];
  const float* bout = (const float*)d_in[14];
  float* out = (float*)d_out;

  const int B = in_sizes[0] / (TT * FF);   // 8192
  dim3 grid(B / BT), block(NT);
  lstm_ae_kernel<<<grid, block, 0, stream>>>(
      x, Wih1, Whh1, b1, Wih2, Whh2, b2, Wih3, Whh3, b3,
      Wih4, Whh4, b4, Wout, bout, out);
}

// Round 3
// 257.940 us; speedup vs baseline: 3.1204x; 3.1204x over previous
//
#include <hip/hip_runtime.h>

// LSTM autoencoder via bf16 MFMA. B=8192, T=30, F=16, H1=64, H2=32.
// Weights permuted unit-major (row = unit*4 + gate) and held in A-frag REGISTERS;
// activations flow through LDS batch-major (aB[batch][kslot], bf16, stride 200).
// C/D layout of mfma_f32_16x16x32_bf16: col=lane&15 (batch), row=quad*4+reg (unit,gate)
// => each lane owns all 4 gates of one unit for one batch; c-state stays in registers.
// kslots phase A: 0..31 x (16 real + 16 zero), 32..95 h1 buf0, 96..159 h1 buf1, 160..191 h2
// kslots phase B: 0..31 h3 buf0, 32..63 h3 buf1, 64..127 h4, 160..191 latent (preserved)
// Grid 512 blocks x 512 thr (BT=16 batches/block) -> 2 blocks/CU, 16 waves/CU.

#define TT 30
#define FF 16

typedef unsigned short u16t;
typedef __attribute__((ext_vector_type(8))) short short8;
typedef __attribute__((ext_vector_type(4))) float floatx4;

#define MFMA(a, b, c) __builtin_amdgcn_mfma_f32_16x16x32_bf16(a, b, c, 0, 0, 0)

__device__ __forceinline__ float sigf(float v) { return 1.f / (1.f + __expf(-v)); }
__device__ __forceinline__ float tanhf_(float v) { return 2.f / (1.f + __expf(-2.f * v)) - 1.f; }
__device__ __forceinline__ u16t f2bf(float f) {
  unsigned int u = __float_as_uint(f);
  u = (u + 0x7FFFu + ((u >> 16) & 1u)) >> 16;
  return (u16t)u;
}

__global__ __launch_bounds__(512, 4) void lstm_ae_mfma(
    const float* __restrict__ x,
    const float* __restrict__ Wih1, const float* __restrict__ Whh1, const float* __restrict__ b1,
    const float* __restrict__ Wih2, const float* __restrict__ Whh2, const float* __restrict__ b2,
    const float* __restrict__ Wih3, const float* __restrict__ Whh3, const float* __restrict__ b3,
    const float* __restrict__ Wih4, const float* __restrict__ Whh4, const float* __restrict__ b4,
    const float* __restrict__ Wout, const float* __restrict__ bout,
    float* __restrict__ out)
{
  __shared__ __align__(16) u16t wL[256 * 104];   // weight staging, row stride 104 bf16
  __shared__ __align__(16) u16t aB[16 * 200];    // activations, batch-major, stride 200 bf16
  __shared__ __align__(16) float bSS[784];       // permuted biases

  const int t = threadIdx.x;
  const int lane = t & 63, w = t >> 6;           // 8 waves
  const int q = lane >> 4, n = lane & 15;        // quad, batch-col (and A-frag row m)
  const int bBase = blockIdx.x * 16;
  const u16t* aRow = &aB[n * 200];

  // ================= init: biases (permuted), zero aB, stage W1 =================
  for (int i = t; i < 784; i += 512) {
    float v;
    if (i < 256)      { int u = i >> 2, gt = i & 3; v = b1[gt * 64 + u]; }
    else if (i < 384) { int j = i - 256, u = j >> 2, gt = j & 3; v = b2[gt * 32 + u]; }
    else if (i < 512) { int j = i - 384, u = j >> 2, gt = j & 3; v = b3[gt * 32 + u]; }
    else if (i < 768) { int j = i - 512, u = j >> 2, gt = j & 3; v = b4[gt * 64 + u]; }
    else              { v = bout[i - 768]; }
    bSS[i] = v;
  }
  for (int i = t; i < 16 * 200; i += 512) aB[i] = 0;
  for (int i = t; i < 256 * 96; i += 512) {      // W1: k<16 Wih1, 16..31 zero, 32..95 Whh1
    int row = i / 96, k = i - row * 96;
    int u = row >> 2, gt = row & 3;
    float v = (k < 16) ? Wih1[(gt * 64 + u) * 16 + k]
            : (k < 32) ? 0.f
                       : Whh1[(gt * 64 + u) * 64 + (k - 32)];
    wL[row * 104 + k] = f2bf(v);
  }
  __syncthreads();
  short8 w1f[2][3];
#pragma unroll
  for (int tt = 0; tt < 2; ++tt)
#pragma unroll
    for (int kt = 0; kt < 3; ++kt)
      w1f[tt][kt] = *(const short8*)&wL[((2 * w + tt) * 16 + n) * 104 + kt * 32 + q * 8];
  if (t < 256) {  // stage x(0)
    int xb = t >> 4, xf = t & 15;
    aB[xb * 200 + xf] = f2bf(x[(size_t)(bBase + xb) * (TT * FF) + xf]);
  }
  __syncthreads();
  for (int i = t; i < 128 * 96; i += 512) {      // W2: k<64 Wih2 (h1), 64..95 Whh2 (h2)
    int row = i / 96, k = i - row * 96;
    int u = row >> 2, gt = row & 3;
    float v = (k < 64) ? Wih2[(gt * 32 + u) * 64 + k]
                       : Whh2[(gt * 32 + u) * 32 + (k - 64)];
    wL[row * 104 + k] = f2bf(v);
  }
  __syncthreads();
  short8 w2f[3];
#pragma unroll
  for (int kt = 0; kt < 3; ++kt)
    w2f[kt] = *(const short8*)&wL[(w * 16 + n) * 104 + kt * 32 + q * 8];
  __syncthreads();

  float c1v[2] = {0.f, 0.f}, c2v = 0.f;

  // ================= Phase A: encoder, 30 steps =================
  for (int st = 0; st < TT; ++st) {
    const int p = st & 1;
    const int h1o = 32 + p * 64, h1n = 32 + (1 - p) * 64;
    __syncthreads();  // h2new(st-1) + x(st) visible
    short8 bx   = *(const short8*)&aRow[q * 8];
    short8 bh1a = *(const short8*)&aRow[h1o + q * 8];
    short8 bh1b = *(const short8*)&aRow[h1o + 32 + q * 8];
    short8 bh2  = *(const short8*)&aRow[160 + q * 8];
    float xv = 0.f;
    if (t < 256 && st + 1 < TT)
      xv = x[(size_t)(bBase + (t >> 4)) * (TT * FF) + (st + 1) * FF + (t & 15)];
    floatx4 a0 = *(const floatx4*)&bSS[(2 * w + 0) * 16 + q * 4];
    floatx4 a1 = *(const floatx4*)&bSS[(2 * w + 1) * 16 + q * 4];
    a0 = MFMA(w1f[0][0], bx, a0);   a1 = MFMA(w1f[1][0], bx, a1);
    a0 = MFMA(w1f[0][1], bh1a, a0); a1 = MFMA(w1f[1][1], bh1a, a1);
    a0 = MFMA(w1f[0][2], bh1b, a0); a1 = MFMA(w1f[1][2], bh1b, a1);
#pragma unroll
    for (int tt = 0; tt < 2; ++tt) {
      floatx4 acc = tt ? a1 : a0;
      float iv = sigf(acc[0]), fv = sigf(acc[1]);
      float gv = tanhf_(acc[2]), ov = sigf(acc[3]);
      float c = fv * c1v[tt] + iv * gv;
      c1v[tt] = c;
      aB[n * 200 + h1n + (2 * w + tt) * 4 + q] = f2bf(ov * tanhf_(c));
    }
    __syncthreads();  // h1new visible
    short8 bh1na = *(const short8*)&aRow[h1n + q * 8];
    short8 bh1nb = *(const short8*)&aRow[h1n + 32 + q * 8];
    if (t < 256 && st + 1 < TT)
      aB[(t >> 4) * 200 + (t & 15)] = f2bf(xv);
    floatx4 a2 = *(const floatx4*)&bSS[256 + w * 16 + q * 4];
    a2 = MFMA(w2f[0], bh1na, a2);
    a2 = MFMA(w2f[1], bh1nb, a2);
    a2 = MFMA(w2f[2], bh2, a2);
    {
      float iv = sigf(a2[0]), fv = sigf(a2[1]);
      float gv = tanhf_(a2[2]), ov = sigf(a2[3]);
      float c = fv * c2v + iv * gv;
      c2v = c;
      aB[n * 200 + 160 + w * 4 + q] = f2bf(ov * tanhf_(c));
    }
  }

  // ================= transition: latent at slots 160..191; stage B weights =================
  __syncthreads();
  for (int i = t; i < 16 * 128; i += 512) {      // re-zero h3/h4 slots 0..127
    int r = i >> 7, kk = i & 127;
    aB[r * 200 + kk] = 0;
  }
  for (int i = t; i < 128 * 64; i += 512) {      // W3: k<32 Wih3 (latent), 32..63 Whh3 (h3)
    int row = i >> 6, k = i & 63;
    int u = row >> 2, gt = row & 3;
    float v = (k < 32) ? Wih3[(gt * 32 + u) * 32 + k]
                       : Whh3[(gt * 32 + u) * 32 + (k - 32)];
    wL[row * 104 + k] = f2bf(v);
  }
  __syncthreads();
  short8 w3f[2];
#pragma unroll
  for (int kt = 0; kt < 2; ++kt)
    w3f[kt] = *(const short8*)&wL[(w * 16 + n) * 104 + kt * 32 + q * 8];
  short8 blat = *(const short8*)&aRow[160 + q * 8];  // static latent B-frag
  __syncthreads();
  for (int i = t; i < 256 * 96; i += 512) {      // W4: k<32 Wih4 (h3), 32..95 Whh4 (h4)
    int row = i / 96, k = i - row * 96;
    int u = row >> 2, gt = row & 3;
    float v = (k < 32) ? Wih4[(gt * 64 + u) * 32 + k]
                       : Whh4[(gt * 64 + u) * 64 + (k - 32)];
    wL[row * 104 + k] = f2bf(v);
  }
  __syncthreads();
  short8 w4f[2][3];
#pragma unroll
  for (int tt = 0; tt < 2; ++tt)
#pragma unroll
    for (int kt = 0; kt < 3; ++kt)
      w4f[tt][kt] = *(const short8*)&wL[((2 * w + tt) * 16 + n) * 104 + kt * 32 + q * 8];
  __syncthreads();
  for (int i = t; i < 16 * 64; i += 512) {       // Wout: 16 x 64, no permute
    int row = i >> 6, k = i & 63;
    wL[row * 104 + k] = f2bf(Wout[row * 64 + k]);
  }
  __syncthreads();
  short8 wof[2];
#pragma unroll
  for (int kt = 0; kt < 2; ++kt)
    wof[kt] = *(const short8*)&wL[n * 104 + kt * 32 + q * 8];

  float c3v = 0.f, c4v[2] = {0.f, 0.f};

  // ================= Phase B: decoder, 30 steps =================
  for (int st = 0; st < TT; ++st) {
    const int p = st & 1;
    const int h3o = p * 32, h3n = (1 - p) * 32;
    __syncthreads();  // h4new(st-1) visible (and init zeros at st=0)
    short8 bh3  = *(const short8*)&aRow[h3o + q * 8];
    short8 bh4a = *(const short8*)&aRow[64 + q * 8];
    short8 bh4b = *(const short8*)&aRow[96 + q * 8];
    floatx4 a3 = *(const floatx4*)&bSS[384 + w * 16 + q * 4];
    a3 = MFMA(w3f[0], blat, a3);
    a3 = MFMA(w3f[1], bh3, a3);
    {
      float iv = sigf(a3[0]), fv = sigf(a3[1]);
      float gv = tanhf_(a3[2]), ov = sigf(a3[3]);
      float c = fv * c3v + iv * gv;
      c3v = c;
      aB[n * 200 + h3n + w * 4 + q] = f2bf(ov * tanhf_(c));
    }
    __syncthreads();  // h3new visible
    short8 bh3nf = *(const short8*)&aRow[h3n + q * 8];
    floatx4 a40 = *(const floatx4*)&bSS[512 + (2 * w + 0) * 16 + q * 4];
    floatx4 a41 = *(const floatx4*)&bSS[512 + (2 * w + 1) * 16 + q * 4];
    a40 = MFMA(w4f[0][0], bh3nf, a40); a41 = MFMA(w4f[1][0], bh3nf, a41);
    a40 = MFMA(w4f[0][1], bh4a, a40);  a41 = MFMA(w4f[1][1], bh4a, a41);
    a40 = MFMA(w4f[0][2], bh4b, a40);  a41 = MFMA(w4f[1][2], bh4b, a41);
#pragma unroll
    for (int tt = 0; tt < 2; ++tt) {
      floatx4 acc = tt ? a41 : a40;
      float iv = sigf(acc[0]), fv = sigf(acc[1]);
      float gv = tanhf_(acc[2]), ov = sigf(acc[3]);
      float c = fv * c4v[tt] + iv * gv;
      c4v[tt] = c;
      aB[n * 200 + 64 + (2 * w + tt) * 4 + q] = f2bf(ov * tanhf_(c));
    }
    __syncthreads();  // h4new visible
    if (w == 0) {
      short8 boa = *(const short8*)&aRow[64 + q * 8];
      short8 bob = *(const short8*)&aRow[96 + q * 8];
      floatx4 yv = *(const floatx4*)&bSS[768 + q * 4];
      yv = MFMA(wof[0], boa, yv);
      yv = MFMA(wof[1], bob, yv);
      *(floatx4*)&out[((size_t)(bBase + n) * TT + st) * FF + q * 4] = yv;
    }
  }
}

extern "C" void kernel_launch(void* const* d_in, const int* in_sizes, int n_in,
                              void* d_out, int out_size, void* d_ws, size_t ws_size,
                              hipStream_t stream) {
  const float* x    = (const float*)d_in[0];
  const float* Wih1 = (const float*)d_in[1];
  const float* Whh1 = (const float*)d_in[2];
  const float* b1   = (const float*)d_in[3];
  const float* Wih2 = (const float*)d_in[4];
  const float* Whh2 = (const float*)d_in[5];
  const float* b2   = (const float*)d_in[6];
  const float* Wih3 = (const float*)d_in[7];
  const float* Whh3 = (const float*)d_in[8];
  const float* b3   = (const float*)d_in[9];
  const float* Wih4 = (const float*)d_in[10];
  const float* Whh4 = (const float*)d_in[11];
  const float* b4   = (const float*)d_in[12];
  const float* Wout = (const float*)d_in[13];
  const float* bout = (const float*)d_in[14];
  float* out = (float*)d_out;

  const int B = in_sizes[0] / (TT * FF);   // 8192
  dim3 grid(B / 16), block(512);
  lstm_ae_mfma<<<grid, block, 0, stream>>>(
      x, Wih1, Whh1, b1, Wih2, Whh2, b2, Wih3, Whh3, b3,
      Wih4, Whh4, b4, Wout, bout, out);
}

// Round 4
// 172.354 us; speedup vs baseline: 4.6700x; 1.4966x over previous
//
#include <hip/hip_runtime.h>

// LSTM autoencoder via bf16 MFMA, v2. B=8192, T=30, F=16, H1=64, H2=32.
// - Weight A-frags + biases loaded ONCE from global directly into registers
//   (unit-major permute row = unit*4+gate makes each lane's 8-k run contiguous).
// - x preloaded to LDS for all 30 steps (stride-968 bf16, zero-padded k=16..31).
// - h4 decoder outputs buffered in LDS for all 30 steps; output projection done
//   by all 8 waves after the loop (no per-step wave0 barrier / store drain).
// - Activations use v_rcp (no fp32 div sequence): sig = rcp(1+exp(-x)),
//   tanh = 1 - 2*rcp(1+exp(2x)).
// - 2 barriers per step everywhere. Grid 512 x 512thr, 16 batches/block.
// LDS: big 63.7KB (xAll phase A / hAll phase B) + aB 6.4KB = ~68.5KB -> 2 blk/CU.
// aB slots: phA: h2 dbuf {0..31,160..191}, h1 dbuf 32..159. phB: latent 0..31
// (preserved = final h2), h3 dbuf 64..127.

#define TT 30
#define FF 16

typedef unsigned short u16t;
typedef __attribute__((ext_vector_type(8))) short short8;
typedef __attribute__((ext_vector_type(4))) short short4v;
typedef __attribute__((ext_vector_type(4))) float floatx4;

#define MFMA(a, b, c) __builtin_amdgcn_mfma_f32_16x16x32_bf16(a, b, c, 0, 0, 0)

__device__ __forceinline__ float rcpf(float v) { return __builtin_amdgcn_rcpf(v); }
__device__ __forceinline__ float sigf(float v) { return rcpf(1.f + __expf(-v)); }
__device__ __forceinline__ float tanhf_(float v) { return 1.f - 2.f * rcpf(1.f + __expf(2.f * v)); }
__device__ __forceinline__ u16t f2bf(float f) {
  unsigned int u = __float_as_uint(f);
  u = (u + 0x7FFFu + ((u >> 16) & 1u)) >> 16;
  return (u16t)u;
}
__device__ __forceinline__ short8 ldFrag(const float* p) {
  const float4 lo = *(const float4*)p;
  const float4 hi = *(const float4*)(p + 4);
  short8 r;
  r[0] = (short)f2bf(lo.x); r[1] = (short)f2bf(lo.y);
  r[2] = (short)f2bf(lo.z); r[3] = (short)f2bf(lo.w);
  r[4] = (short)f2bf(hi.x); r[5] = (short)f2bf(hi.y);
  r[6] = (short)f2bf(hi.z); r[7] = (short)f2bf(hi.w);
  return r;
}
// lane owns gates i,f,g,o of one (unit,batch) in acc regs 0..3
__device__ __forceinline__ float cellUp(const floatx4 acc, float& c) {
  float iv = sigf(acc[0]), fv = sigf(acc[1]);
  float gv = tanhf_(acc[2]), ov = sigf(acc[3]);
  c = fv * c + iv * gv;
  return ov * tanhf_(c);
}

__global__ __launch_bounds__(512, 4) void lstm_ae_mfma2(
    const float* __restrict__ x,
    const float* __restrict__ Wih1, const float* __restrict__ Whh1, const float* __restrict__ b1,
    const float* __restrict__ Wih2, const float* __restrict__ Whh2, const float* __restrict__ b2,
    const float* __restrict__ Wih3, const float* __restrict__ Whh3, const float* __restrict__ b3,
    const float* __restrict__ Wih4, const float* __restrict__ Whh4, const float* __restrict__ b4,
    const float* __restrict__ Wout, const float* __restrict__ bout,
    float* __restrict__ out)
{
  __shared__ __align__(16) u16t big[16 * 1992];  // phA: xAll stride 968; phB: hAll stride 1992
  __shared__ __align__(16) u16t aB[16 * 200];    // recurrent activations, stride 200

  const int t = threadIdx.x;
  const int w = t >> 6, lane = t & 63;
  const int q = lane >> 4, n = lane & 15;
  const int q8 = q * 8, n200 = n * 200;
  const int n968 = n * 968, n1992 = n * 1992;
  const int bBase = blockIdx.x * 16;
  const int nlo = n >> 2, ngt = n & 3;

  // ================= init: zero aB, preload x, load phase-A weights/biases =================
  for (int i = t; i < 16 * 200; i += 512) aB[i] = 0;
  {
    const float* xb = x + (size_t)bBase * (TT * FF);
    for (int i4 = t; i4 < 1920; i4 += 512) {
      int e = i4 * 4;
      int b = e / 480, r = e - b * 480;
      int stp = r >> 4, f = r & 15;
      float4 v = *(const float4*)&xb[e];
      short4v s4 = { (short)f2bf(v.x), (short)f2bf(v.y), (short)f2bf(v.z), (short)f2bf(v.w) };
      *(short4v*)&big[b * 968 + stp * 32 + f] = s4;
    }
    for (int i = t; i < 7680; i += 512) {   // zero pads k=16..31
      int b = i / 480, r = i - b * 480;
      int stp = r >> 4, f = r & 15;
      big[b * 968 + stp * 32 + 16 + f] = 0;
    }
  }
  short8 w1f[2][3]; floatx4 bias1[2];
  const short8 z8 = { 0, 0, 0, 0, 0, 0, 0, 0 };
#pragma unroll
  for (int tt = 0; tt < 2; ++tt) {
    int row = ngt * 64 + (2 * w + tt) * 4 + nlo;
    w1f[tt][0] = z8;
    if (q < 2) w1f[tt][0] = ldFrag(&Wih1[row * 16 + q8]);
    w1f[tt][1] = ldFrag(&Whh1[row * 64 + q8]);
    w1f[tt][2] = ldFrag(&Whh1[row * 64 + 32 + q8]);
#pragma unroll
    for (int r = 0; r < 4; ++r) bias1[tt][r] = b1[r * 64 + (2 * w + tt) * 4 + q];
  }
  short8 w2f[3]; floatx4 bias2;
  {
    int row = ngt * 32 + w * 4 + nlo;
    w2f[0] = ldFrag(&Wih2[row * 64 + q8]);
    w2f[1] = ldFrag(&Wih2[row * 64 + 32 + q8]);
    w2f[2] = ldFrag(&Whh2[row * 32 + q8]);
#pragma unroll
    for (int r = 0; r < 4; ++r) bias2[r] = b2[r * 32 + w * 4 + q];
  }
  __syncthreads();

  float c1v[2] = {0.f, 0.f}, c2v = 0.f;

  // ================= Phase A: encoder =================
  for (int st = 0; st < TT; ++st) {
    const int p = st & 1;
    const int h1o = 32 + p * 64, h1n = 32 + (1 - p) * 64;
    const int h2o = p ? 160 : 0, h2n = p ? 0 : 160;
    const short8 bx   = *(const short8*)&big[n968 + st * 32 + q8];
    const short8 bh1a = *(const short8*)&aB[n200 + h1o + q8];
    const short8 bh1b = *(const short8*)&aB[n200 + h1o + 32 + q8];
    const short8 bh2  = *(const short8*)&aB[n200 + h2o + q8];
    floatx4 a0 = bias1[0], a1 = bias1[1];
    a0 = MFMA(w1f[0][0], bx, a0);   a1 = MFMA(w1f[1][0], bx, a1);
    a0 = MFMA(w1f[0][1], bh1a, a0); a1 = MFMA(w1f[1][1], bh1a, a1);
    a0 = MFMA(w1f[0][2], bh1b, a0); a1 = MFMA(w1f[1][2], bh1b, a1);
    aB[n200 + h1n + (2 * w) * 4 + q]     = f2bf(cellUp(a0, c1v[0]));
    aB[n200 + h1n + (2 * w + 1) * 4 + q] = f2bf(cellUp(a1, c1v[1]));
    __syncthreads();  // h1new visible
    const short8 bh1na = *(const short8*)&aB[n200 + h1n + q8];
    const short8 bh1nb = *(const short8*)&aB[n200 + h1n + 32 + q8];
    floatx4 a2 = bias2;
    a2 = MFMA(w2f[0], bh1na, a2);
    a2 = MFMA(w2f[1], bh1nb, a2);
    a2 = MFMA(w2f[2], bh2, a2);
    aB[n200 + h2n + w * 4 + q] = f2bf(cellUp(a2, c2v));
    __syncthreads();  // h2new visible
  }
  // final h2 (latent) is at slots 0..31 (st=29: p=1 -> h2n=0)

  // ================= transition: load phase-B weights/biases, zero h3 + hAll[0] =================
  const short8 blat = *(const short8*)&aB[n200 + q8];
  short8 w3f[2]; floatx4 bias3;
  {
    int row = ngt * 32 + w * 4 + nlo;
    w3f[0] = ldFrag(&Wih3[row * 32 + q8]);
    w3f[1] = ldFrag(&Whh3[row * 32 + q8]);
#pragma unroll
    for (int r = 0; r < 4; ++r) bias3[r] = b3[r * 32 + w * 4 + q];
  }
  short8 w4f[2][3]; floatx4 bias4[2];
#pragma unroll
  for (int tt = 0; tt < 2; ++tt) {
    int row = ngt * 64 + (2 * w + tt) * 4 + nlo;
    w4f[tt][0] = ldFrag(&Wih4[row * 32 + q8]);
    w4f[tt][1] = ldFrag(&Whh4[row * 64 + q8]);
    w4f[tt][2] = ldFrag(&Whh4[row * 64 + 32 + q8]);
#pragma unroll
    for (int r = 0; r < 4; ++r) bias4[tt][r] = b4[r * 64 + (2 * w + tt) * 4 + q];
  }
  short8 wof[2];
  wof[0] = ldFrag(&Wout[n * 64 + q8]);
  wof[1] = ldFrag(&Wout[n * 64 + 32 + q8]);
  const floatx4 biasO = *(const floatx4*)&bout[q * 4];
  for (int i = t; i < 1024; i += 512) aB[(i >> 6) * 200 + 64 + (i & 63)] = 0;  // h3 dbuf
  for (int i = t; i < 1024; i += 512) big[(i >> 6) * 1992 + (i & 63)] = 0;     // hAll step -1
  __syncthreads();

  float c3v = 0.f, c4v[2] = {0.f, 0.f};

  // ================= Phase B: decoder =================
  for (int st = 0; st < TT; ++st) {
    const int p = st & 1;
    const int h3o = 64 + p * 32, h3n = 64 + (1 - p) * 32;
    const short8 bh3  = *(const short8*)&aB[n200 + h3o + q8];
    const short8 bh4a = *(const short8*)&big[n1992 + st * 64 + q8];
    const short8 bh4b = *(const short8*)&big[n1992 + st * 64 + 32 + q8];
    floatx4 a3 = bias3;
    a3 = MFMA(w3f[0], blat, a3);
    a3 = MFMA(w3f[1], bh3, a3);
    aB[n200 + h3n + w * 4 + q] = f2bf(cellUp(a3, c3v));
    __syncthreads();  // h3new visible
    const short8 bh3n = *(const short8*)&aB[n200 + h3n + q8];
    floatx4 a40 = bias4[0], a41 = bias4[1];
    a40 = MFMA(w4f[0][0], bh3n, a40); a41 = MFMA(w4f[1][0], bh3n, a41);
    a40 = MFMA(w4f[0][1], bh4a, a40); a41 = MFMA(w4f[1][1], bh4a, a41);
    a40 = MFMA(w4f[0][2], bh4b, a40); a41 = MFMA(w4f[1][2], bh4b, a41);
    big[n1992 + (st + 1) * 64 + (2 * w) * 4 + q]     = f2bf(cellUp(a40, c4v[0]));
    big[n1992 + (st + 1) * 64 + (2 * w + 1) * 4 + q] = f2bf(cellUp(a41, c4v[1]));
    __syncthreads();  // h4(st) visible
  }

  // ================= output projection: wave w handles steps 4w..4w+3 =================
  for (int s = w * 4; s < w * 4 + 4 && s < TT; ++s) {
    const short8 ba = *(const short8*)&big[n1992 + (s + 1) * 64 + q8];
    const short8 bb = *(const short8*)&big[n1992 + (s + 1) * 64 + 32 + q8];
    floatx4 yv = biasO;
    yv = MFMA(wof[0], ba, yv);
    yv = MFMA(wof[1], bb, yv);
    *(floatx4*)&out[((size_t)(bBase + n) * TT + s) * FF + q * 4] = yv;
  }
}

extern "C" void kernel_launch(void* const* d_in, const int* in_sizes, int n_in,
                              void* d_out, int out_size, void* d_ws, size_t ws_size,
                              hipStream_t stream) {
  const float* x    = (const float*)d_in[0];
  const float* Wih1 = (const float*)d_in[1];
  const float* Whh1 = (const float*)d_in[2];
  const float* b1   = (const float*)d_in[3];
  const float* Wih2 = (const float*)d_in[4];
  const float* Whh2 = (const float*)d_in[5];
  const float* b2   = (const float*)d_in[6];
  const float* Wih3 = (const float*)d_in[7];
  const float* Whh3 = (const float*)d_in[8];
  const float* b3   = (const float*)d_in[9];
  const float* Wih4 = (const float*)d_in[10];
  const float* Whh4 = (const float*)d_in[11];
  const float* b4   = (const float*)d_in[12];
  const float* Wout = (const float*)d_in[13];
  const float* bout = (const float*)d_in[14];
  float* out = (float*)d_out;

  const int B = in_sizes[0] / (TT * FF);   // 8192
  dim3 grid(B / 16), block(512);
  lstm_ae_mfma2<<<grid, block, 0, stream>>>(
      x, Wih1, Whh1, b1, Wih2, Whh2, b2, Wih3, Whh3, b3,
      Wih4, Whh4, b4, Wout, bout, out);
}

// Round 5
// 171.653 us; speedup vs baseline: 4.6890x; 1.0041x over previous
//
#include <hip/hip_runtime.h>

// LSTM autoencoder via bf16 MFMA, v3: skewed pipeline, ONE barrier per step.
// B=8192, T=30, F=16, H1=64, H2=32. Grid 512 x 512 thr, 16 batches/block.
// Skew: z2(st) and z1(st+1) both depend only on h1(st) -> one sync region.
//       z4(st) and z3(st+1) both depend only on h3(st); proj(st-1) reuses the
//       h4(st-1) B-frags z4(st) already loaded (rotating wave, no extra reads).
// Weights/biases live in registers (unit-major permute row=unit*4+gate).
// aB slots (stride 264 u16; 132 words = 4 mod 32 -> exactly-2-way LDS alias, free):
//   phase A: h1 dbuf p*64 (0..127), h2 dbuf 128+p*32 (128..191)
//   phase B: latent 160..191 (= final h2, preserved), h3 dbuf 192+p*32, h4 dbuf p*64
// LDS: xAll 16x968 u16 (31.0KB) + aB 16x264 u16 (8.4KB) = 39.4KB.

#define TT 30
#define FF 16

typedef unsigned short u16t;
typedef __attribute__((ext_vector_type(8))) short short8;
typedef __attribute__((ext_vector_type(4))) short short4v;
typedef __attribute__((ext_vector_type(4))) float floatx4;

#define MFMA(a, b, c) __builtin_amdgcn_mfma_f32_16x16x32_bf16(a, b, c, 0, 0, 0)

__device__ __forceinline__ float rcpf(float v) { return __builtin_amdgcn_rcpf(v); }
__device__ __forceinline__ float sigf(float v) { return rcpf(1.f + __expf(-v)); }
__device__ __forceinline__ float tanhf_(float v) { return 1.f - 2.f * rcpf(1.f + __expf(2.f * v)); }
__device__ __forceinline__ u16t f2bf(float f) {
  unsigned int u = __float_as_uint(f);
  u = (u + 0x7FFFu + ((u >> 16) & 1u)) >> 16;
  return (u16t)u;
}
__device__ __forceinline__ short8 ldFrag(const float* p) {
  const float4 lo = *(const float4*)p;
  const float4 hi = *(const float4*)(p + 4);
  short8 r;
  r[0] = (short)f2bf(lo.x); r[1] = (short)f2bf(lo.y);
  r[2] = (short)f2bf(lo.z); r[3] = (short)f2bf(lo.w);
  r[4] = (short)f2bf(hi.x); r[5] = (short)f2bf(hi.y);
  r[6] = (short)f2bf(hi.z); r[7] = (short)f2bf(hi.w);
  return r;
}
// lane owns gates i,f,g,o of one (unit,batch): acc regs 0..3
__device__ __forceinline__ float cellUp(const floatx4 acc, float& c) {
  float iv = sigf(acc[0]), fv = sigf(acc[1]);
  float gv = tanhf_(acc[2]), ov = sigf(acc[3]);
  c = fv * c + iv * gv;
  return ov * tanhf_(c);
}

__global__ __launch_bounds__(512, 4) void lstm_ae_mfma3(
    const float* __restrict__ x,
    const float* __restrict__ Wih1, const float* __restrict__ Whh1, const float* __restrict__ b1,
    const float* __restrict__ Wih2, const float* __restrict__ Whh2, const float* __restrict__ b2,
    const float* __restrict__ Wih3, const float* __restrict__ Whh3, const float* __restrict__ b3,
    const float* __restrict__ Wih4, const float* __restrict__ Whh4, const float* __restrict__ b4,
    const float* __restrict__ Wout, const float* __restrict__ bout,
    float* __restrict__ out)
{
  __shared__ __align__(16) u16t xAll[16 * 968];  // x bf16, k=16..31 zero-padded, stride 968
  __shared__ __align__(16) u16t aB[16 * 264];    // recurrent state, stride 264

  const int t = threadIdx.x;
  const int w = t >> 6, lane = t & 63;
  const int q = lane >> 4, n = lane & 15;
  const int q8 = q * 8, n264 = n * 264, n968 = n * 968;
  const int bBase = blockIdx.x * 16;
  const int nlo = n >> 2, ngt = n & 3;
  const u16t* aRow = &aB[n264];

  // ================= init: zero aB, preload x, load phase-A weights/biases =================
  for (int i = t; i < 16 * 264; i += 512) aB[i] = 0;
  {
    const float* xb = x + (size_t)bBase * (TT * FF);
    for (int i4 = t; i4 < 1920; i4 += 512) {
      int e = i4 * 4;
      int b = e / 480, r = e - b * 480;
      int stp = r >> 4, f = r & 15;
      float4 v = *(const float4*)&xb[e];
      short4v s4 = { (short)f2bf(v.x), (short)f2bf(v.y), (short)f2bf(v.z), (short)f2bf(v.w) };
      *(short4v*)&xAll[b * 968 + stp * 32 + f] = s4;
    }
    for (int i = t; i < 7680; i += 512) {   // zero pads k=16..31
      int b = i / 480, r = i - b * 480;
      int stp = r >> 4, f = r & 15;
      xAll[b * 968 + stp * 32 + 16 + f] = 0;
    }
  }
  short8 w1f[2][3]; floatx4 bias1[2];
  const short8 z8 = { 0, 0, 0, 0, 0, 0, 0, 0 };
#pragma unroll
  for (int tt = 0; tt < 2; ++tt) {
    int row = ngt * 64 + (2 * w + tt) * 4 + nlo;
    w1f[tt][0] = z8;
    if (q < 2) w1f[tt][0] = ldFrag(&Wih1[row * 16 + q8]);
    w1f[tt][1] = ldFrag(&Whh1[row * 64 + q8]);
    w1f[tt][2] = ldFrag(&Whh1[row * 64 + 32 + q8]);
#pragma unroll
    for (int r = 0; r < 4; ++r) bias1[tt][r] = b1[r * 64 + (2 * w + tt) * 4 + q];
  }
  short8 w2f[3]; floatx4 bias2;
  {
    int row = ngt * 32 + w * 4 + nlo;
    w2f[0] = ldFrag(&Wih2[row * 64 + q8]);
    w2f[1] = ldFrag(&Wih2[row * 64 + 32 + q8]);
    w2f[2] = ldFrag(&Whh2[row * 32 + q8]);
#pragma unroll
    for (int r = 0; r < 4; ++r) bias2[r] = b2[r * 32 + w * 4 + q];
  }
  __syncthreads();

  float c1v[2] = {0.f, 0.f}, c2v = 0.f;

  // ---- peel: z1(0) = bias1 + W1x*x(0)   (h1(-1)=0) ----
  {
    const short8 bx = *(const short8*)&xAll[n968 + q8];
    floatx4 a0 = bias1[0], a1 = bias1[1];
    a0 = MFMA(w1f[0][0], bx, a0); a1 = MFMA(w1f[1][0], bx, a1);
    aB[n264 + (2 * w) * 4 + q]     = f2bf(cellUp(a0, c1v[0]));
    aB[n264 + (2 * w + 1) * 4 + q] = f2bf(cellUp(a1, c1v[1]));
  }
  __syncthreads();

  // ================= Phase A: 29 skewed iters, ONE barrier each =================
  for (int st = 0; st < TT - 1; ++st) {
    const int p = st & 1;
    const short8 bh1a = *(const short8*)&aRow[p * 64 + q8];
    const short8 bh1b = *(const short8*)&aRow[p * 64 + 32 + q8];
    const short8 bh2  = *(const short8*)&aRow[128 + (1 - p) * 32 + q8];
    const short8 bx   = *(const short8*)&xAll[n968 + (st + 1) * 32 + q8];
    // z2(st)
    floatx4 a2 = bias2;
    a2 = MFMA(w2f[0], bh1a, a2);
    a2 = MFMA(w2f[1], bh1b, a2);
    a2 = MFMA(w2f[2], bh2, a2);
    // z1(st+1)
    floatx4 a0 = bias1[0], a1 = bias1[1];
    a0 = MFMA(w1f[0][0], bx, a0);   a1 = MFMA(w1f[1][0], bx, a1);
    a0 = MFMA(w1f[0][1], bh1a, a0); a1 = MFMA(w1f[1][1], bh1a, a1);
    a0 = MFMA(w1f[0][2], bh1b, a0); a1 = MFMA(w1f[1][2], bh1b, a1);
    aB[n264 + 128 + p * 32 + w * 4 + q]        = f2bf(cellUp(a2, c2v));
    aB[n264 + (1 - p) * 64 + (2 * w) * 4 + q]  = f2bf(cellUp(a0, c1v[0]));
    aB[n264 + (1 - p) * 64 + (2 * w + 1) * 4 + q] = f2bf(cellUp(a1, c1v[1]));
    __syncthreads();
  }
  // ---- peel: z2(29); h1(29) in buf1 (64..), h2(28) in buf0 (128..) -> latent 160..191 ----
  {
    const short8 bh1a = *(const short8*)&aRow[64 + q8];
    const short8 bh1b = *(const short8*)&aRow[96 + q8];
    const short8 bh2  = *(const short8*)&aRow[128 + q8];
    floatx4 a2 = bias2;
    a2 = MFMA(w2f[0], bh1a, a2);
    a2 = MFMA(w2f[1], bh1b, a2);
    a2 = MFMA(w2f[2], bh2, a2);
    aB[n264 + 160 + w * 4 + q] = f2bf(cellUp(a2, c2v));
  }
  __syncthreads();

  // ================= transition: load B weights, zero h4(-1) buf, grab latent =================
  short8 w3f[2]; floatx4 bias3;
  {
    int row = ngt * 32 + w * 4 + nlo;
    w3f[0] = ldFrag(&Wih3[row * 32 + q8]);
    w3f[1] = ldFrag(&Whh3[row * 32 + q8]);
#pragma unroll
    for (int r = 0; r < 4; ++r) bias3[r] = b3[r * 32 + w * 4 + q];
  }
  short8 w4f[2][3]; floatx4 bias4[2];
#pragma unroll
  for (int tt = 0; tt < 2; ++tt) {
    int row = ngt * 64 + (2 * w + tt) * 4 + nlo;
    w4f[tt][0] = ldFrag(&Wih4[row * 32 + q8]);
    w4f[tt][1] = ldFrag(&Whh4[row * 64 + q8]);
    w4f[tt][2] = ldFrag(&Whh4[row * 64 + 32 + q8]);
#pragma unroll
    for (int r = 0; r < 4; ++r) bias4[tt][r] = b4[r * 64 + (2 * w + tt) * 4 + q];
  }
  short8 wof[2];
  wof[0] = ldFrag(&Wout[n * 64 + q8]);
  wof[1] = ldFrag(&Wout[n * 64 + 32 + q8]);
  const floatx4 biasO = *(const floatx4*)&bout[q * 4];
  const short8 blat = *(const short8*)&aRow[160 + q8];
  for (int i = t; i < 1024; i += 512) aB[(i >> 6) * 264 + 64 + (i & 63)] = 0;  // h4(-1)=0
  __syncthreads();

  float c3v = 0.f, c4v[2] = {0.f, 0.f};

  // ---- peel: z3(0) = bias3 + W3lat*latent   (h3(-1)=0) ----
  {
    floatx4 a3 = bias3;
    a3 = MFMA(w3f[0], blat, a3);
    aB[n264 + 192 + w * 4 + q] = f2bf(cellUp(a3, c3v));
  }
  __syncthreads();

  // ================= Phase B: 29 skewed iters, ONE barrier each =================
  for (int st = 0; st < TT - 1; ++st) {
    const int p = st & 1;
    const short8 bh3  = *(const short8*)&aRow[192 + p * 32 + q8];
    const short8 bh4a = *(const short8*)&aRow[(1 - p) * 64 + q8];
    const short8 bh4b = *(const short8*)&aRow[(1 - p) * 64 + 32 + q8];
    // z4(st)
    floatx4 a40 = bias4[0], a41 = bias4[1];
    a40 = MFMA(w4f[0][0], bh3, a40);  a41 = MFMA(w4f[1][0], bh3, a41);
    a40 = MFMA(w4f[0][1], bh4a, a40); a41 = MFMA(w4f[1][1], bh4a, a41);
    a40 = MFMA(w4f[0][2], bh4b, a40); a41 = MFMA(w4f[1][2], bh4b, a41);
    // z3(st+1)
    floatx4 a3 = bias3;
    a3 = MFMA(w3f[0], blat, a3);
    a3 = MFMA(w3f[1], bh3, a3);
    aB[n264 + p * 64 + (2 * w) * 4 + q]     = f2bf(cellUp(a40, c4v[0]));
    aB[n264 + p * 64 + (2 * w + 1) * 4 + q] = f2bf(cellUp(a41, c4v[1]));
    aB[n264 + 192 + (1 - p) * 32 + w * 4 + q] = f2bf(cellUp(a3, c3v));
    // proj(st-1): rotating wave, reuses bh4a/bh4b (= h4(st-1) frags)
    if (st > 0 && w == ((st - 1) & 7)) {
      floatx4 yv = biasO;
      yv = MFMA(wof[0], bh4a, yv);
      yv = MFMA(wof[1], bh4b, yv);
      *(floatx4*)&out[((size_t)(bBase + n) * TT + (st - 1)) * FF + q * 4] = yv;
    }
    __syncthreads();
  }
  // ---- tail: z4(29) (h3(29) buf1 @224, h4(28) buf0 @0); proj(28); proj(29) ----
  {
    const short8 bh3  = *(const short8*)&aRow[224 + q8];
    const short8 bh4a = *(const short8*)&aRow[q8];
    const short8 bh4b = *(const short8*)&aRow[32 + q8];
    floatx4 a40 = bias4[0], a41 = bias4[1];
    a40 = MFMA(w4f[0][0], bh3, a40);  a41 = MFMA(w4f[1][0], bh3, a41);
    a40 = MFMA(w4f[0][1], bh4a, a40); a41 = MFMA(w4f[1][1], bh4a, a41);
    a40 = MFMA(w4f[0][2], bh4b, a40); a41 = MFMA(w4f[1][2], bh4b, a41);
    aB[n264 + 64 + (2 * w) * 4 + q]     = f2bf(cellUp(a40, c4v[0]));
    aB[n264 + 64 + (2 * w + 1) * 4 + q] = f2bf(cellUp(a41, c4v[1]));
    if (w == 4) {  // proj(28) from h4(28) frags
      floatx4 yv = biasO;
      yv = MFMA(wof[0], bh4a, yv);
      yv = MFMA(wof[1], bh4b, yv);
      *(floatx4*)&out[((size_t)(bBase + n) * TT + 28) * FF + q * 4] = yv;
    }
  }
  __syncthreads();
  if (w == 5) {  // proj(29): h4(29) in buf1 @64
    const short8 ba = *(const short8*)&aRow[64 + q8];
    const short8 bb = *(const short8*)&aRow[96 + q8];
    floatx4 yv = biasO;
    yv = MFMA(wof[0], ba, yv);
    yv = MFMA(wof[1], bb, yv);
    *(floatx4*)&out[((size_t)(bBase + n) * TT + 29) * FF + q * 4] = yv;
  }
}

extern "C" void kernel_launch(void* const* d_in, const int* in_sizes, int n_in,
                              void* d_out, int out_size, void* d_ws, size_t ws_size,
                              hipStream_t stream) {
  const float* x    = (const float*)d_in[0];
  const float* Wih1 = (const float*)d_in[1];
  const float* Whh1 = (const float*)d_in[2];
  const float* b1   = (const float*)d_in[3];
  const float* Wih2 = (const float*)d_in[4];
  const float* Whh2 = (const float*)d_in[5];
  const float* b2   = (const float*)d_in[6];
  const float* Wih3 = (const float*)d_in[7];
  const float* Whh3 = (const float*)d_in[8];
  const float* b3   = (const float*)d_in[9];
  const float* Wih4 = (const float*)d_in[10];
  const float* Whh4 = (const float*)d_in[11];
  const float* b4   = (const float*)d_in[12];
  const float* Wout = (const float*)d_in[13];
  const float* bout = (const float*)d_in[14];
  float* out = (float*)d_out;

  const int B = in_sizes[0] / (TT * FF);   // 8192
  dim3 grid(B / 16), block(512);
  lstm_ae_mfma3<<<grid, block, 0, stream>>>(
      x, Wih1, Whh1, b1, Wih2, Whh2, b2, Wih3, Whh3, b3,
      Wih4, Whh4, b4, Wout, bout, out);
}